// Round 11
// baseline (27.170 us; speedup 1.0000x reference)
//
#include <hip/hip_runtime.h>
#include <math.h>

#define SZ 28

__constant__ int c_fy[10] = {4,4,4,14,14,14,24,24,24,12};
__constant__ int c_fx[10] = {4,14,24,4,14,24,4,14,24,12};

typedef __attribute__((ext_vector_type(4)))  float    f32x4;
typedef __attribute__((ext_vector_type(16))) float    f32x16;
typedef __attribute__((ext_vector_type(8)))  _Float16 f16x8;

// ---------------------------------------------------------------------------
// Fully fused kernel. Per block (64 rows, 512 thr = 8 waves = mtile m x
// kstep-quarter kq):
//  Phase A: 28-pt DFT table (784 terms, STRIDED over 512 threads) -> g1[28].
//  Phase B: W = e^{i phase} * outer(g1,g1)-gather, written as f16 MFMA
//           B-fragments into a 49 KB LDS region (layout = verified R8 prep:
//           frag f16 idx = s*512 + (b*32+v)*8 + j; lane l of kstep s holds
//           B[k=s*16+(l>>5)*8+j][col=l&31]).
//  Phase C: wave (m,kq) copies its 14 B-frags to registers; kq==3 pads with
//           a zero fragment (static indexing).
//  Phase D: R9 streaming loop; bufA (2x14336) aliases the dead W region.
//  Epilogue: 4-way K reduction + |.|^2, out[row][p] = Re^2+Im^2.
// ---------------------------------------------------------------------------
__global__ __launch_bounds__(512) void focus_fused(const float* __restrict__ x,
                                                   const float* __restrict__ phase,
                                                   float* __restrict__ out) {
    __shared__ char smem[50176];                 // W region / bufA / red
    __shared__ float g1r[SZ], g1i[SZ];

    const int tid  = threadIdx.x;
    const int lane = tid & 63;
    const int w = __builtin_amdgcn_readfirstlane(tid >> 6);  // 0..7
    const int m = w >> 2;                                    // mtile
    const int kq = w & 3;                                    // kstep quarter
    const int row0 = blockIdx.x * 64;

    // ---- Phase A: DFT table (strided fill!) + g1 reduction ----
    {
        float* tr = (float*)smem;                // [784]
        float* ti = tr + 784;                    // [784]
        for (int e = tid; e < 784; e += 512) {   // FIX: 512 thr cover 784
            const int t = e / SZ, k = e % SZ;
            const int mm = (k <= SZ / 2) ? k : SZ - k;
            int num = (14 * k * t - mm * mm) % 392; if (num < 0) num += 392;
            float sn, cs;
            sincosf((float)num * (6.283185307179586f / 392.0f), &sn, &cs);
            tr[e] = cs; ti[e] = sn;
        }
        __syncthreads();
        if (tid < SZ) {
            float ar = 0.f, ai = 0.f;
            for (int k = 0; k < SZ; ++k) { ar += tr[tid * SZ + k]; ai += ti[tid * SZ + k]; }
            g1r[tid] = ar / 28.f; g1i[tid] = ai / 28.f;
        }
        __syncthreads();
    }

    // ---- Phase B: W fragments into LDS (overwrites dead DFT table) ----
    {
        _Float16* Wf = (_Float16*)smem;          // 49*512 f16 = 50176 B
        for (int k = tid; k < 784; k += 512) {
            const int y = k / SZ, xx = k % SZ;
            float sp, cp; sincosf(phase[k], &sp, &cp);
            float Wv[20];
            #pragma unroll
            for (int p = 0; p < 10; ++p) {
                const int dy = (c_fy[p] - y + SZ) % SZ;
                const int dx = (c_fx[p] - xx + SZ) % SZ;
                const float Gr = g1r[dy] * g1r[dx] - g1i[dy] * g1i[dx];
                const float Gi = g1r[dy] * g1i[dx] + g1i[dy] * g1r[dx];
                Wv[p]      = cp * Gr - sp * Gi;   // Re
                Wv[10 + p] = cp * Gi + sp * Gr;   // Im
            }
            const int s = k >> 4, b = (k >> 3) & 1, j = k & 7;
            #pragma unroll
            for (int v = 0; v < 32; ++v) {
                float val = 0.f;
                if (v < 20) val = (v & 1) ? Wv[10 + (v >> 1)] : Wv[v >> 1];
                Wf[s * 512 + (b * 32 + v) * 8 + j] = (_Float16)val;
            }
        }
        __syncthreads();
    }

    // ---- Phase C: B fragments to registers (static indices) ----
    f16x8 bfr[14];
    #pragma unroll
    for (int c = 0; c < 7; ++c) {
        {
            const int ks = c * 7 + 2 * kq;       // kq==3 -> kstep 6 of chunk
            bfr[2 * c] = *(const f16x8*)(smem + ks * 1024 + lane * 16);
        }
        if (kq < 3) {
            const int ks = c * 7 + 2 * kq + 1;
            bfr[2 * c + 1] = *(const f16x8*)(smem + ks * 1024 + lane * 16);
        } else {
            f16x8 z;
            #pragma unroll
            for (int i = 0; i < 8; ++i) z[i] = (_Float16)0.f;
            bfr[2 * c + 1] = z;                  // pad: B=0 -> MFMA no-op
        }
    }
    __syncthreads();                             // all W reads done

    // ---- Phase D: streaming loop (bufA aliases smem) ----
    f32x16 acc;
    #pragma unroll
    for (int i = 0; i < 16; ++i) acc[i] = 0.f;

    char* const bA0 = smem;                      // 2 x 14336

    auto loadA = [&](f32x4* v, int c) {
        const f32x4* x4 = (const f32x4*)x;
        #pragma unroll
        for (int i = 0; i < 4; ++i) {
            const int g = i * 512 + tid;
            if (g < 1792) {
                const int r = g / 28, c4 = g % 28;
                v[i] = x4[(size_t)(row0 + r) * 196 + c * 28 + c4];
            }
        }
    };
    auto writeA = [&](const f32x4* v, int c) {
        char* buf = bA0 + (c & 1) * 14336;
        #pragma unroll
        for (int i = 0; i < 4; ++i) {
            const int g = i * 512 + tid;
            if (g < 1792) {
                const int r = g / 28, c4 = g % 28;
                const int s = c4 >> 2, b = (c4 >> 1) & 1;
                const int mt = r >> 5;
                const int ln = ((r & 31) + (b << 5)) ^ s;
                auto lo = __builtin_amdgcn_cvt_pkrtz(v[i].x, v[i].y);
                auto hi = __builtin_amdgcn_cvt_pkrtz(v[i].z, v[i].w);
                uint2 d;
                d.x = __builtin_bit_cast(unsigned int, lo);
                d.y = __builtin_bit_cast(unsigned int, hi);
                *(uint2*)(buf + ((s * 2 + mt) * 64 + ln) * 16 + (c4 & 1) * 8) = d;
            }
        }
    };

    f32x4 v[4];
    loadA(v, 0); writeA(v, 0);
    #pragma unroll
    for (int c = 0; c < 7; ++c) {
        __syncthreads();                         // publishes chunk c bufA
        if (c < 6) loadA(v, c + 1);
        {
            char* bA = bA0 + (c & 1) * 14336;
            #pragma unroll
            for (int sl = 0; sl < 2; ++sl) {
                const int s = (kq == 3) ? 6 : 2 * kq + sl;   // A kstep in chunk
                f16x8 a = *(const f16x8*)(bA + ((s * 2 + m) * 64 + (lane ^ s)) * 16);
                acc = __builtin_amdgcn_mfma_f32_32x32x16_f16(a, bfr[2 * c + sl],
                                                             acc, 0, 0, 0);
            }
        }
        if (c < 6) writeA(v, c + 1);
    }

    // ---- Epilogue: 4-way K reduction per mtile + |.|^2 ----
    __syncthreads();
    float* red = (float*)smem;                   // [2][3][64][17] = 26112 B
    if (kq > 0) {
        #pragma unroll
        for (int i = 0; i < 16; ++i)
            red[((m * 3 + (kq - 1)) * 64 + lane) * 17 + i] = acc[i];
    }
    __syncthreads();
    if (kq == 0) {
        const int col = lane & 31;
        #pragma unroll
        for (int i = 0; i < 16; ++i) {
            const float sum = acc[i]
                + red[((m * 3 + 0) * 64 + lane) * 17 + i]
                + red[((m * 3 + 1) * 64 + lane) * 17 + i]
                + red[((m * 3 + 2) * 64 + lane) * 17 + i];
            const float sq = sum * sum;
            const float tot = sq + __shfl_xor(sq, 1, 64);
            if ((col & 1) == 0 && col < 20) {
                const int r = (i & 3) + 8 * (i >> 2) + 4 * (lane >> 5);
                out[(size_t)(row0 + m * 32 + r) * 10 + (col >> 1)] = tot;
            }
        }
    }
}

extern "C" void kernel_launch(void* const* d_in, const int* in_sizes, int n_in,
                              void* d_out, int out_size, void* d_ws, size_t ws_size,
                              hipStream_t stream) {
    const float* x     = (const float*)d_in[0];   // [32768,1,28,28] f32
    const float* phase = (const float*)d_in[1];   // [28,28] f32
    float* out = (float*)d_out;                   // [32768,10] f32

    const int B = in_sizes[0] / (SZ * SZ);        // 32768
    hipLaunchKernelGGL(focus_fused, dim3(B / 64), dim3(512), 0, stream,
                       x, phase, out);
}